// Round 19
// baseline (269.334 us; speedup 1.0000x reference)
//
#include <hip/hip_runtime.h>

// B=64,T=128,D=U=1024. M=8192 independent rows.
//   h' = reset?0:state
//   z = sig(x@wi_z + h'@wh_z + bz); r = sig(x@wi_r + h'@wh_r + br)
//   a = tanh(x@wi_a + (r*h')@wh_a + ba)   // (r*h') @ w  — * binds left of @
//   h_new = (1-z)h' + z*a; out = [h_new, h_new]
// Round 18: champion schedule, but B operand goes GLOBAL->REGISTER (prefetched
// one tile ahead), A stays global_load_lds-staged. Halves LDS traffic
// (96->48KB per block-tile; LDS-BW floor 60->30us for zr). LDS 2x16KB,
// 2 blocks/CU, counted vmcnt(16).

typedef __attribute__((ext_vector_type(8))) short short8;
typedef __attribute__((ext_vector_type(4))) short short4v;
typedef __attribute__((ext_vector_type(4))) float floatx4;
typedef __attribute__((ext_vector_type(4))) float f32x4;

#define MROWS 8192
#define KTOT 2048
#define NU 1024
#define NKT 32            // K-tiles of 64
#define TBUF 16384        // A only: 128 rows x 128B
#define TLDS (2 * TBUF)   // 32KB

__device__ __forceinline__ short f2bf(float f) {
  unsigned u = __builtin_bit_cast(unsigned, f);
  u += 0x7fffu + ((u >> 16) & 1u);  // RNE
  return (short)(u >> 16);
}
__device__ __forceinline__ float bf2f(short s) {
  unsigned u = ((unsigned)(unsigned short)s) << 16;
  return __builtin_bit_cast(float, u);
}
__device__ __forceinline__ float sigmoid_f(float v) { return 1.f / (1.f + __expf(-v)); }
__device__ __forceinline__ float tanh_f(float v) {
  float c = fminf(fmaxf(v, -15.f), 15.f);
  float e = __expf(2.f * c);
  return (e - 1.f) / (e + 1.f);
}

typedef __attribute__((address_space(3))) void* lds_vp;
typedef const __attribute__((address_space(1))) void* gbl_vp;
__device__ __forceinline__ void gload16(const void* g, void* lds) {
  __builtin_amdgcn_global_load_lds((gbl_vp)g, (lds_vp)lds, 16, 0, 0);
}

#define MF(a, b, c) __builtin_amdgcn_mfma_f32_16x16x32_bf16(a, b, c, 0, 0, 0)
#define VMCNT(n) asm volatile("s_waitcnt vmcnt(" #n ")" ::: "memory")
#define LGKM0() asm volatile("s_waitcnt lgkmcnt(0)" ::: "memory")
#define TILE_BAR()                  \
  do {                              \
    __builtin_amdgcn_s_barrier();   \
    asm volatile("" ::: "memory");  \
  } while (0)

// ---- merged prep: blocks [0,6144): Wc transpose; [6144,14336): xh convert ---
__global__ __launch_bounds__(256) void prep_kernel(
    const float* __restrict__ w_i, const float* __restrict__ w_h,
    short* __restrict__ Wc, const float* __restrict__ x,
    const int* __restrict__ reset, const float* __restrict__ state,
    short* __restrict__ xhc) {
  __shared__ float tile[32][33];
  const int b = blockIdx.x;
  if (b < 6144) {
    const int kb = (b & 63) * 32;
    const int nb = (b >> 6) * 32;
    const float* src = (kb < 1024) ? w_i : w_h;
    const int kbl = kb & 1023;
    const int tx = threadIdx.x & 31;
    const int ty = threadIdx.x >> 5;
#pragma unroll
    for (int r = 0; r < 32; r += 8)
      tile[ty + r][tx] = src[(size_t)(kbl + ty + r) * 3072 + nb + tx];
    __syncthreads();
#pragma unroll
    for (int r = 0; r < 32; r += 8)
      Wc[(size_t)(nb + ty + r) * KTOT + kb + tx] = f2bf(tile[tx][ty + r]);
  } else {
    const size_t i4 = (size_t)(b - 6144) * 256 + threadIdx.x;
    const size_t e = i4 * 4;
    const int row = (int)(e >> 10);
    const int d = (int)(e & 1023);
    const float hm = reset[row] ? 0.f : 1.f;
    floatx4 fx = *(const floatx4*)(x + e);
    floatx4 fh = *(const floatx4*)(state + e);
    short4v cx, ch;
#pragma unroll
    for (int k = 0; k < 4; ++k) { cx[k] = f2bf(fx[k]); ch[k] = f2bf(fh[k] * hm); }
    *(short4v*)(xhc + (size_t)row * KTOT + d) = cx;
    *(short4v*)(xhc + (size_t)row * KTOT + 1024 + d) = ch;
  }
}

// ================= zr: 128x128 tile, 4 waves, per-wave 64x64 =================
__global__ __launch_bounds__(256, 2) void zr_kernel(
    const short* __restrict__ xhc, const short* __restrict__ Wc,
    const float* __restrict__ bias, float* __restrict__ zbuf,
    short* __restrict__ rh) {
  extern __shared__ char lds[];
  const int tid = threadIdx.x;
  const int wave = tid >> 6, lane = tid & 63;
  const int wm = wave >> 1, wn = wave & 1;   // 2M x 2N waves
  const int lrow = lane & 15;
  const int g16 = (lane >> 4) << 4;
  const int swz = (lrow & 7) << 4;           // read-side XOR (verified: 0 conflicts)
  const int srow = lane >> 3;                // staging row within 8-group
  const int scol = ((lane & 7) ^ srow) * 8;  // pre-swizzled global k-col (shorts)

  const int xcd = blockIdx.x & 7, bi = blockIdx.x >> 3;  // 1024 blocks
  const int mtile = xcd * 8 + (bi & 7);      // A-chunk 4MB L2-resident per XCD
  const int ntile = bi >> 3;                 // 0..15
  const int m0 = mtile * 128, n0g = ntile * 128;

  const short* aS = xhc + (size_t)(m0 + wave * 32 + srow) * KTOT + scol;
  // B fragment base: row = n0g + wn*64 + j*16 + lrow, col = t*64 + ks*32 + (lane>>4)*8
  const short* bR = Wc + (size_t)(n0g + wn * 64 + lrow) * KTOT + ((lane >> 4) << 3);
  const int dA = wave * 4096;

  f32x4 acc[4][4];
#pragma unroll
  for (int i = 0; i < 4; ++i)
#pragma unroll
    for (int j = 0; j < 4; ++j) acc[i][j] = (f32x4){0.f, 0.f, 0.f, 0.f};

  short8 bq0[2][4], bq1[2][4];  // two named prefetch sets (static indexing)

#define ZR_STAGE(t, bufp)                                                  \
  _Pragma("unroll") for (int g = 0; g < 4; ++g)                            \
    gload16(aS + (size_t)g * 8 * KTOT + (t) * 64, (bufp) + dA + g * 1024);

#define LOADB(tt, B)                                                       \
  _Pragma("unroll") for (int j = 0; j < 4; ++j)                            \
    _Pragma("unroll") for (int ks = 0; ks < 2; ++ks)                       \
      B[ks][j] = *(const short8*)(bR + (size_t)(j * 16) * KTOT +           \
                                  (tt) * 64 + ks * 32);

// one K-tile: ds_read A both ks -> MFMA ks0 -> LGKM0+BAR (WAR) ->
// stage A(t+2) + prefetch B(t+1) -> MFMA ks1 -> vmcnt(16)+BAR
#define ZR_BODY(T, BCUR, BNXT)                                             \
  {                                                                        \
    char* buf = lds + ((T) & 1) * TBUF;                                    \
    short8 af[2][4];                                                       \
    _Pragma("unroll") for (int ks = 0; ks < 2; ++ks) {                     \
      const int colb = ((ks * 64 + g16) ^ swz);                            \
      const char* pA = buf + (wm * 64 + lrow) * 128 + colb;                \
      _Pragma("unroll") for (int i = 0; i < 4; ++i)                        \
        af[ks][i] = *(const short8*)(pA + i * 2048);                       \
    }                                                                      \
    __builtin_amdgcn_s_setprio(1);                                         \
    _Pragma("unroll") for (int i = 0; i < 4; ++i)                          \
      _Pragma("unroll") for (int j = 0; j < 4; ++j)                        \
        acc[i][j] = MF(af[0][i], BCUR[0][j], acc[i][j]);                   \
    __builtin_amdgcn_s_setprio(0);                                         \
    LGKM0();       /* this wave's A reads done (WAR) */                    \
    TILE_BAR();    /* block-wide: safe to stage into buf */                \
    if ((T) + 2 < NKT) { ZR_STAGE((T) + 2, buf); }                         \
    if ((T) + 1 < NKT) { LOADB((T) + 1, BNXT); }                           \
    __builtin_amdgcn_s_setprio(1);                                         \
    _Pragma("unroll") for (int i = 0; i < 4; ++i)                          \
      _Pragma("unroll") for (int j = 0; j < 4; ++j)                        \
        acc[i][j] = MF(af[1][i], BCUR[1][j], acc[i][j]);                   \
    __builtin_amdgcn_s_setprio(0);                                         \
    if ((T) + 1 < NKT) { VMCNT(16); }  /* A(t+1) landed (20 issued after) */ \
    TILE_BAR();                                                            \
  }

  ZR_STAGE(0, lds);
  ZR_STAGE(1, lds + TBUF);
  LOADB(0, bq0);
  VMCNT(12);   // A(0)'s 4 landed (12 issued after)
  TILE_BAR();

  for (int t = 0; t < NKT; t += 2) {
    ZR_BODY(t, bq0, bq1);
    ZR_BODY(t + 1, bq1, bq0);
  }
#undef ZR_BODY
#undef ZR_STAGE
#undef LOADB

  const bool zh = (n0g < 1024);
#pragma unroll
  for (int j = 0; j < 4; ++j) {
    const int gcn = n0g + wn * 64 + j * 16 + lrow;
    const float bv = bias[gcn];
#pragma unroll
    for (int i = 0; i < 4; ++i) {
#pragma unroll
      for (int rg = 0; rg < 4; ++rg) {
        const int gr = m0 + wm * 64 + i * 16 + (lane >> 4) * 4 + rg;
        const float sv = sigmoid_f(acc[i][j][rg] + bv);
        if (zh) {
          zbuf[(size_t)gr * NU + gcn] = sv;
        } else {
          const int u = gcn - 1024;
          const float hv = bf2f(xhc[(size_t)gr * KTOT + 1024 + u]);
          rh[(size_t)gr * NU + u] = f2bf(sv * hv);
        }
      }
    }
  }
}

// ================= cand: 128x128 tile, 4 waves, per-wave 64x64 =================
__global__ __launch_bounds__(256, 2) void cand_kernel(
    const short* __restrict__ xhc, const short* __restrict__ rh,
    const short* __restrict__ Wc, const float* __restrict__ bias,
    const float* zbuf, float* out) {  // zbuf/out alias d_out: no restrict
  extern __shared__ char lds[];
  const int tid = threadIdx.x;
  const int wave = tid >> 6, lane = tid & 63;
  const int wm = wave >> 1, wn = wave & 1;
  const int lrow = lane & 15;
  const int g16 = (lane >> 4) << 4;
  const int swz = (lrow & 7) << 4;
  const int srow = lane >> 3;
  const int scol = ((lane & 7) ^ srow) * 8;

  const int xcd = blockIdx.x & 7, bi = blockIdx.x >> 3;  // 512 blocks
  const int mtile = xcd * 8 + (bi & 7);
  const int ntile = bi >> 3;                 // 0..7
  const int m0 = mtile * 128, n0g = ntile * 128;

  const short* aX = xhc + (size_t)(m0 + wave * 32 + srow) * KTOT + scol;  // x cols
  const short* aR = rh + (size_t)(m0 + wave * 32 + srow) * NU + scol;
  const short* bR = Wc + (size_t)(2048 + n0g + wn * 64 + lrow) * KTOT + ((lane >> 4) << 3);
  const int dA = wave * 4096;

  f32x4 acc[4][4];
#pragma unroll
  for (int i = 0; i < 4; ++i)
#pragma unroll
    for (int j = 0; j < 4; ++j) acc[i][j] = (f32x4){0.f, 0.f, 0.f, 0.f};

  short8 bq0[2][4], bq1[2][4];

  // A: tiles 0..15 from x-half (stride KTOT), 16..31 from rh (stride NU)
#define CD_STAGE(t, bufp)                                                      \
  _Pragma("unroll") for (int g = 0; g < 4; ++g) {                              \
    if ((t) < 16)                                                              \
      gload16(aX + (size_t)g * 8 * KTOT + (t) * 64, (bufp) + dA + g * 1024);   \
    else                                                                       \
      gload16(aR + (size_t)g * 8 * NU + ((t) - 16) * 64,                       \
              (bufp) + dA + g * 1024);                                         \
  }

#define LOADB(tt, B)                                                       \
  _Pragma("unroll") for (int j = 0; j < 4; ++j)                            \
    _Pragma("unroll") for (int ks = 0; ks < 2; ++ks)                       \
      B[ks][j] = *(const short8*)(bR + (size_t)(j * 16) * KTOT +           \
                                  (tt) * 64 + ks * 32);

#define CD_BODY(T, BCUR, BNXT)                                             \
  {                                                                        \
    char* buf = lds + ((T) & 1) * TBUF;                                    \
    short8 af[2][4];                                                       \
    _Pragma("unroll") for (int ks = 0; ks < 2; ++ks) {                     \
      const int colb = ((ks * 64 + g16) ^ swz);                            \
      const char* pA = buf + (wm * 64 + lrow) * 128 + colb;                \
      _Pragma("unroll") for (int i = 0; i < 4; ++i)                        \
        af[ks][i] = *(const short8*)(pA + i * 2048);                       \
    }                                                                      \
    __builtin_amdgcn_s_setprio(1);                                         \
    _Pragma("unroll") for (int i = 0; i < 4; ++i)                          \
      _Pragma("unroll") for (int j = 0; j < 4; ++j)                        \
        acc[i][j] = MF(af[0][i], BCUR[0][j], acc[i][j]);                   \
    __builtin_amdgcn_s_setprio(0);                                         \
    LGKM0();                                                               \
    TILE_BAR();                                                            \
    if ((T) + 2 < NKT) { CD_STAGE((T) + 2, buf); }                         \
    if ((T) + 1 < NKT) { LOADB((T) + 1, BNXT); }                           \
    __builtin_amdgcn_s_setprio(1);                                         \
    _Pragma("unroll") for (int i = 0; i < 4; ++i)                          \
      _Pragma("unroll") for (int j = 0; j < 4; ++j)                        \
        acc[i][j] = MF(af[1][i], BCUR[1][j], acc[i][j]);                   \
    __builtin_amdgcn_s_setprio(0);                                         \
    if ((T) + 1 < NKT) { VMCNT(16); }                                      \
    TILE_BAR();                                                            \
  }

  CD_STAGE(0, lds);
  CD_STAGE(1, lds + TBUF);
  LOADB(0, bq0);
  VMCNT(12);
  TILE_BAR();

  for (int t = 0; t < NKT; t += 2) {
    CD_BODY(t, bq0, bq1);
    CD_BODY(t + 1, bq1, bq0);
  }
#undef CD_BODY
#undef CD_STAGE
#undef LOADB

#pragma unroll
  for (int j = 0; j < 4; ++j) {
    const int gc = n0g + wn * 64 + j * 16 + lrow;
    const float ba = bias[2048 + gc];
#pragma unroll
    for (int i = 0; i < 4; ++i) {
#pragma unroll
      for (int rg = 0; rg < 4; ++rg) {
        const int gr = m0 + wm * 64 + i * 16 + (lane >> 4) * 4 + rg;
        const float av = tanh_f(acc[i][j][rg] + ba);
        const float zv = zbuf[(size_t)gr * NU + gc];
        const float hv = bf2f(xhc[(size_t)gr * KTOT + 1024 + gc]);
        const float hn = (1.f - zv) * hv + zv * av;
        out[(size_t)gr * NU + gc] = hn;
        out[(size_t)MROWS * NU + (size_t)gr * NU + gc] = hn;  // overwrites zbuf slot (read-first, same thread)
      }
    }
  }
}

extern "C" void kernel_launch(void* const* d_in, const int* in_sizes, int n_in,
                              void* d_out, int out_size, void* d_ws, size_t ws_size,
                              hipStream_t stream) {
  const float* x = (const float*)d_in[0];
  const int* reset = (const int*)d_in[1];
  const float* state = (const float*)d_in[2];
  const float* w_i = (const float*)d_in[3];
  const float* w_h = (const float*)d_in[4];
  const float* bias = (const float*)d_in[5];
  float* out = (float*)d_out;

  short* Wc = (short*)d_ws;                    // [3072][2048] bf16, 12.6MB
  short* xhc = Wc + (size_t)3072 * KTOT;       // [8192][2048] bf16, 33.5MB
  short* rh = xhc + (size_t)MROWS * KTOT;      // [8192][1024] bf16, 16.8MB
  float* zbuf = out + (size_t)MROWS * NU;      // z in d_out 2nd half

  hipFuncSetAttribute(reinterpret_cast<const void*>(zr_kernel),
                      hipFuncAttributeMaxDynamicSharedMemorySize, TLDS);
  hipFuncSetAttribute(reinterpret_cast<const void*>(cand_kernel),
                      hipFuncAttributeMaxDynamicSharedMemorySize, TLDS);

  // merged prep: 6144 transpose blocks + 8192 convert blocks
  prep_kernel<<<dim3(14336), 256, 0, stream>>>(w_i, w_h, Wc, x, reset, state, xhc);

  zr_kernel<<<dim3(1024), 256, TLDS, stream>>>(xhc, Wc, bias, zbuf, rh);
  cand_kernel<<<dim3(512), 256, TLDS, stream>>>(xhc, rh, Wc, bias, zbuf, out);
}

// Round 20
// 266.474 us; speedup vs baseline: 1.0107x; 1.0107x over previous
//
#include <hip/hip_runtime.h>

// B=64,T=128,D=U=1024. M=8192 independent rows.
//   h' = reset?0:state
//   z = sig(x@wi_z + h'@wh_z + bz); r = sig(x@wi_r + h'@wh_r + br)
//   a = tanh(x@wi_a + (r*h')@wh_a + ba)   // (r*h') @ w  — * binds left of @
//   h_new = (1-z)h' + z*a; out = [h_new, h_new]
// Round 19: B global->register with DISTANCE-2 prefetch (fixes r18's exposed
// L2 latency: B(t+2) loaded at end of tile t into the just-freed set, cover =
// one full K-tile). A stays global_load_lds-staged (champion swizzle).
// LDS 2x16KB (A only) -> half the champion's LDS traffic.

typedef __attribute__((ext_vector_type(8))) short short8;
typedef __attribute__((ext_vector_type(4))) short short4v;
typedef __attribute__((ext_vector_type(4))) float floatx4;
typedef __attribute__((ext_vector_type(4))) float f32x4;

#define MROWS 8192
#define KTOT 2048
#define NU 1024
#define NKT 32            // K-tiles of 64
#define TBUF 16384        // A only: 128 rows x 128B
#define TLDS (2 * TBUF)   // 32KB

__device__ __forceinline__ short f2bf(float f) {
  unsigned u = __builtin_bit_cast(unsigned, f);
  u += 0x7fffu + ((u >> 16) & 1u);  // RNE
  return (short)(u >> 16);
}
__device__ __forceinline__ float bf2f(short s) {
  unsigned u = ((unsigned)(unsigned short)s) << 16;
  return __builtin_bit_cast(float, u);
}
__device__ __forceinline__ float sigmoid_f(float v) { return 1.f / (1.f + __expf(-v)); }
__device__ __forceinline__ float tanh_f(float v) {
  float c = fminf(fmaxf(v, -15.f), 15.f);
  float e = __expf(2.f * c);
  return (e - 1.f) / (e + 1.f);
}

typedef __attribute__((address_space(3))) void* lds_vp;
typedef const __attribute__((address_space(1))) void* gbl_vp;
__device__ __forceinline__ void gload16(const void* g, void* lds) {
  __builtin_amdgcn_global_load_lds((gbl_vp)g, (lds_vp)lds, 16, 0, 0);
}

#define MF(a, b, c) __builtin_amdgcn_mfma_f32_16x16x32_bf16(a, b, c, 0, 0, 0)
#define VMCNT(n) asm volatile("s_waitcnt vmcnt(" #n ")" ::: "memory")
#define LGKM0() asm volatile("s_waitcnt lgkmcnt(0)" ::: "memory")
#define TILE_BAR()                  \
  do {                              \
    __builtin_amdgcn_s_barrier();   \
    asm volatile("" ::: "memory");  \
  } while (0)

// ---- merged prep: blocks [0,6144): Wc transpose; [6144,14336): xh convert ---
__global__ __launch_bounds__(256) void prep_kernel(
    const float* __restrict__ w_i, const float* __restrict__ w_h,
    short* __restrict__ Wc, const float* __restrict__ x,
    const int* __restrict__ reset, const float* __restrict__ state,
    short* __restrict__ xhc) {
  __shared__ float tile[32][33];
  const int b = blockIdx.x;
  if (b < 6144) {
    const int kb = (b & 63) * 32;
    const int nb = (b >> 6) * 32;
    const float* src = (kb < 1024) ? w_i : w_h;
    const int kbl = kb & 1023;
    const int tx = threadIdx.x & 31;
    const int ty = threadIdx.x >> 5;
#pragma unroll
    for (int r = 0; r < 32; r += 8)
      tile[ty + r][tx] = src[(size_t)(kbl + ty + r) * 3072 + nb + tx];
    __syncthreads();
#pragma unroll
    for (int r = 0; r < 32; r += 8)
      Wc[(size_t)(nb + ty + r) * KTOT + kb + tx] = f2bf(tile[tx][ty + r]);
  } else {
    const size_t i4 = (size_t)(b - 6144) * 256 + threadIdx.x;
    const size_t e = i4 * 4;
    const int row = (int)(e >> 10);
    const int d = (int)(e & 1023);
    const float hm = reset[row] ? 0.f : 1.f;
    floatx4 fx = *(const floatx4*)(x + e);
    floatx4 fh = *(const floatx4*)(state + e);
    short4v cx, ch;
#pragma unroll
    for (int k = 0; k < 4; ++k) { cx[k] = f2bf(fx[k]); ch[k] = f2bf(fh[k] * hm); }
    *(short4v*)(xhc + (size_t)row * KTOT + d) = cx;
    *(short4v*)(xhc + (size_t)row * KTOT + 1024 + d) = ch;
  }
}

// ================= zr: 128x128 tile, 4 waves, per-wave 64x64 =================
__global__ __launch_bounds__(256, 2) void zr_kernel(
    const short* __restrict__ xhc, const short* __restrict__ Wc,
    const float* __restrict__ bias, float* __restrict__ zbuf,
    short* __restrict__ rh) {
  extern __shared__ char lds[];
  const int tid = threadIdx.x;
  const int wave = tid >> 6, lane = tid & 63;
  const int wm = wave >> 1, wn = wave & 1;   // 2M x 2N waves
  const int lrow = lane & 15;
  const int g16 = (lane >> 4) << 4;
  const int swz = (lrow & 7) << 4;           // read-side XOR (verified: 0 conflicts)
  const int srow = lane >> 3;                // staging row within 8-group
  const int scol = ((lane & 7) ^ srow) * 8;  // pre-swizzled global k-col (shorts)

  const int xcd = blockIdx.x & 7, bi = blockIdx.x >> 3;  // 1024 blocks
  const int mtile = xcd * 8 + (bi & 7);      // A-chunk 4MB L2-resident per XCD
  const int ntile = bi >> 3;                 // 0..15
  const int m0 = mtile * 128, n0g = ntile * 128;

  const short* aS = xhc + (size_t)(m0 + wave * 32 + srow) * KTOT + scol;
  // B fragment: row = n0g + wn*64 + j*16 + lrow, col = t*64 + ks*32 + (lane>>4)*8
  const short* bR = Wc + (size_t)(n0g + wn * 64 + lrow) * KTOT + ((lane >> 4) << 3);
  const int dA = wave * 4096;

  f32x4 acc[4][4];
#pragma unroll
  for (int i = 0; i < 4; ++i)
#pragma unroll
    for (int j = 0; j < 4; ++j) acc[i][j] = (f32x4){0.f, 0.f, 0.f, 0.f};

  short8 bq0[2][4], bq1[2][4];  // two named prefetch sets, distance-2 rotation

#define ZR_STAGE(t, bufp)                                                  \
  _Pragma("unroll") for (int g = 0; g < 4; ++g)                            \
    gload16(aS + (size_t)g * 8 * KTOT + (t) * 64, (bufp) + dA + g * 1024);

#define LOADB(tt, B)                                                       \
  _Pragma("unroll") for (int j = 0; j < 4; ++j)                            \
    _Pragma("unroll") for (int ks = 0; ks < 2; ++ks)                       \
      B[ks][j] = *(const short8*)(bR + (size_t)(j * 16) * KTOT +           \
                                  (tt) * 64 + ks * 32);

// one K-tile: ds_read A -> MFMA ks0 (B in regs, loaded 2 tiles ago) ->
// LGKM0+BAR (WAR) -> stage A(t+2) -> MFMA ks1 -> LOADB(t+2 into freed set)
// -> counted vmcnt -> BAR
#define ZR_BODY(T, BSET)                                                   \
  {                                                                        \
    char* buf = lds + ((T) & 1) * TBUF;                                    \
    short8 af[2][4];                                                       \
    _Pragma("unroll") for (int ks = 0; ks < 2; ++ks) {                     \
      const int colb = ((ks * 64 + g16) ^ swz);                            \
      const char* pA = buf + (wm * 64 + lrow) * 128 + colb;                \
      _Pragma("unroll") for (int i = 0; i < 4; ++i)                        \
        af[ks][i] = *(const short8*)(pA + i * 2048);                       \
    }                                                                      \
    __builtin_amdgcn_s_setprio(1);                                         \
    _Pragma("unroll") for (int i = 0; i < 4; ++i)                          \
      _Pragma("unroll") for (int j = 0; j < 4; ++j)                        \
        acc[i][j] = MF(af[0][i], BSET[0][j], acc[i][j]);                   \
    __builtin_amdgcn_s_setprio(0);                                         \
    LGKM0();       /* this wave's A reads done (WAR) */                    \
    TILE_BAR();    /* block-wide: safe to stage into buf */                \
    if ((T) + 2 < NKT) { ZR_STAGE((T) + 2, buf); }                         \
    __builtin_amdgcn_s_setprio(1);                                         \
    _Pragma("unroll") for (int i = 0; i < 4; ++i)                          \
      _Pragma("unroll") for (int j = 0; j < 4; ++j)                        \
        acc[i][j] = MF(af[1][i], BSET[1][j], acc[i][j]);                   \
    __builtin_amdgcn_s_setprio(0);                                         \
    if ((T) + 2 < NKT) { LOADB((T) + 2, BSET); }  /* set free after ks1 */ \
    if ((T) + 2 < NKT) { VMCNT(20); }             /* A(T+1) landed */      \
    else if ((T) + 1 < NKT) { VMCNT(8); }                                  \
    TILE_BAR();                                                            \
  }

  ZR_STAGE(0, lds);
  ZR_STAGE(1, lds + TBUF);
  LOADB(0, bq0);
  LOADB(1, bq1);
  VMCNT(20);   // A(0)'s 4 landed (A(1)4 + B(0)8 + B(1)8 = 20 after)
  TILE_BAR();

  for (int t = 0; t < NKT; t += 2) {
    ZR_BODY(t, bq0);
    ZR_BODY(t + 1, bq1);
  }
#undef ZR_BODY
#undef ZR_STAGE
#undef LOADB

  const bool zh = (n0g < 1024);
#pragma unroll
  for (int j = 0; j < 4; ++j) {
    const int gcn = n0g + wn * 64 + j * 16 + lrow;
    const float bv = bias[gcn];
#pragma unroll
    for (int i = 0; i < 4; ++i) {
#pragma unroll
      for (int rg = 0; rg < 4; ++rg) {
        const int gr = m0 + wm * 64 + i * 16 + (lane >> 4) * 4 + rg;
        const float sv = sigmoid_f(acc[i][j][rg] + bv);
        if (zh) {
          zbuf[(size_t)gr * NU + gcn] = sv;
        } else {
          const int u = gcn - 1024;
          const float hv = bf2f(xhc[(size_t)gr * KTOT + 1024 + u]);
          rh[(size_t)gr * NU + u] = f2bf(sv * hv);
        }
      }
    }
  }
}

// ================= cand: 128x128 tile, 4 waves, per-wave 64x64 =================
__global__ __launch_bounds__(256, 2) void cand_kernel(
    const short* __restrict__ xhc, const short* __restrict__ rh,
    const short* __restrict__ Wc, const float* __restrict__ bias,
    const float* zbuf, float* out) {  // zbuf/out alias d_out: no restrict
  extern __shared__ char lds[];
  const int tid = threadIdx.x;
  const int wave = tid >> 6, lane = tid & 63;
  const int wm = wave >> 1, wn = wave & 1;
  const int lrow = lane & 15;
  const int g16 = (lane >> 4) << 4;
  const int swz = (lrow & 7) << 4;
  const int srow = lane >> 3;
  const int scol = ((lane & 7) ^ srow) * 8;

  const int xcd = blockIdx.x & 7, bi = blockIdx.x >> 3;  // 512 blocks
  const int mtile = xcd * 8 + (bi & 7);
  const int ntile = bi >> 3;                 // 0..7
  const int m0 = mtile * 128, n0g = ntile * 128;

  const short* aX = xhc + (size_t)(m0 + wave * 32 + srow) * KTOT + scol;  // x cols
  const short* aR = rh + (size_t)(m0 + wave * 32 + srow) * NU + scol;
  const short* bR = Wc + (size_t)(2048 + n0g + wn * 64 + lrow) * KTOT + ((lane >> 4) << 3);
  const int dA = wave * 4096;

  f32x4 acc[4][4];
#pragma unroll
  for (int i = 0; i < 4; ++i)
#pragma unroll
    for (int j = 0; j < 4; ++j) acc[i][j] = (f32x4){0.f, 0.f, 0.f, 0.f};

  short8 bq0[2][4], bq1[2][4];

  // A: tiles 0..15 from x-half (stride KTOT), 16..31 from rh (stride NU)
#define CD_STAGE(t, bufp)                                                      \
  _Pragma("unroll") for (int g = 0; g < 4; ++g) {                              \
    if ((t) < 16)                                                              \
      gload16(aX + (size_t)g * 8 * KTOT + (t) * 64, (bufp) + dA + g * 1024);   \
    else                                                                       \
      gload16(aR + (size_t)g * 8 * NU + ((t) - 16) * 64,                       \
              (bufp) + dA + g * 1024);                                         \
  }

#define LOADB(tt, B)                                                       \
  _Pragma("unroll") for (int j = 0; j < 4; ++j)                            \
    _Pragma("unroll") for (int ks = 0; ks < 2; ++ks)                       \
      B[ks][j] = *(const short8*)(bR + (size_t)(j * 16) * KTOT +           \
                                  (tt) * 64 + ks * 32);

#define CD_BODY(T, BSET)                                                   \
  {                                                                        \
    char* buf = lds + ((T) & 1) * TBUF;                                    \
    short8 af[2][4];                                                       \
    _Pragma("unroll") for (int ks = 0; ks < 2; ++ks) {                     \
      const int colb = ((ks * 64 + g16) ^ swz);                            \
      const char* pA = buf + (wm * 64 + lrow) * 128 + colb;                \
      _Pragma("unroll") for (int i = 0; i < 4; ++i)                        \
        af[ks][i] = *(const short8*)(pA + i * 2048);                       \
    }                                                                      \
    __builtin_amdgcn_s_setprio(1);                                         \
    _Pragma("unroll") for (int i = 0; i < 4; ++i)                          \
      _Pragma("unroll") for (int j = 0; j < 4; ++j)                        \
        acc[i][j] = MF(af[0][i], BSET[0][j], acc[i][j]);                   \
    __builtin_amdgcn_s_setprio(0);                                         \
    LGKM0();                                                               \
    TILE_BAR();                                                            \
    if ((T) + 2 < NKT) { CD_STAGE((T) + 2, buf); }                         \
    __builtin_amdgcn_s_setprio(1);                                         \
    _Pragma("unroll") for (int i = 0; i < 4; ++i)                          \
      _Pragma("unroll") for (int j = 0; j < 4; ++j)                        \
        acc[i][j] = MF(af[1][i], BSET[1][j], acc[i][j]);                   \
    __builtin_amdgcn_s_setprio(0);                                         \
    if ((T) + 2 < NKT) { LOADB((T) + 2, BSET); }                           \
    if ((T) + 2 < NKT) { VMCNT(20); }                                      \
    else if ((T) + 1 < NKT) { VMCNT(8); }                                  \
    TILE_BAR();                                                            \
  }

  CD_STAGE(0, lds);
  CD_STAGE(1, lds + TBUF);
  LOADB(0, bq0);
  LOADB(1, bq1);
  VMCNT(20);
  TILE_BAR();

  for (int t = 0; t < NKT; t += 2) {
    CD_BODY(t, bq0);
    CD_BODY(t + 1, bq1);
  }
#undef CD_BODY
#undef CD_STAGE
#undef LOADB

#pragma unroll
  for (int j = 0; j < 4; ++j) {
    const int gc = n0g + wn * 64 + j * 16 + lrow;
    const float ba = bias[2048 + gc];
#pragma unroll
    for (int i = 0; i < 4; ++i) {
#pragma unroll
      for (int rg = 0; rg < 4; ++rg) {
        const int gr = m0 + wm * 64 + i * 16 + (lane >> 4) * 4 + rg;
        const float av = tanh_f(acc[i][j][rg] + ba);
        const float zv = zbuf[(size_t)gr * NU + gc];
        const float hv = bf2f(xhc[(size_t)gr * KTOT + 1024 + gc]);
        const float hn = (1.f - zv) * hv + zv * av;
        out[(size_t)gr * NU + gc] = hn;
        out[(size_t)MROWS * NU + (size_t)gr * NU + gc] = hn;  // overwrites zbuf slot (read-first, same thread)
      }
    }
  }
}

extern "C" void kernel_launch(void* const* d_in, const int* in_sizes, int n_in,
                              void* d_out, int out_size, void* d_ws, size_t ws_size,
                              hipStream_t stream) {
  const float* x = (const float*)d_in[0];
  const int* reset = (const int*)d_in[1];
  const float* state = (const float*)d_in[2];
  const float* w_i = (const float*)d_in[3];
  const float* w_h = (const float*)d_in[4];
  const float* bias = (const float*)d_in[5];
  float* out = (float*)d_out;

  short* Wc = (short*)d_ws;                    // [3072][2048] bf16, 12.6MB
  short* xhc = Wc + (size_t)3072 * KTOT;       // [8192][2048] bf16, 33.5MB
  short* rh = xhc + (size_t)MROWS * KTOT;      // [8192][1024] bf16, 16.8MB
  float* zbuf = out + (size_t)MROWS * NU;      // z in d_out 2nd half

  hipFuncSetAttribute(reinterpret_cast<const void*>(zr_kernel),
                      hipFuncAttributeMaxDynamicSharedMemorySize, TLDS);
  hipFuncSetAttribute(reinterpret_cast<const void*>(cand_kernel),
                      hipFuncAttributeMaxDynamicSharedMemorySize, TLDS);

  // merged prep: 6144 transpose blocks + 8192 convert blocks
  prep_kernel<<<dim3(14336), 256, 0, stream>>>(w_i, w_h, Wc, x, reset, state, xhc);

  zr_kernel<<<dim3(1024), 256, TLDS, stream>>>(xhc, Wc, bias, zbuf, rh);
  cand_kernel<<<dim3(512), 256, TLDS, stream>>>(xhc, rh, Wc, bias, zbuf, out);
}